// Round 12
// baseline (280.609 us; speedup 1.0000x reference)
//
#include <hip/hip_runtime.h>
#include <hip/hip_bf16.h>

#define HH 1024
#define NHEADS 8
#define HDIM 128
#define BB 4
#define TT 2048
#define MROWS (BB*TT)   // 8192

typedef __bf16 bf16;
typedef __bf16 bf16x4 __attribute__((ext_vector_type(4)));
typedef __bf16 bf16x8 __attribute__((ext_vector_type(8)));
typedef float floatx4 __attribute__((ext_vector_type(4)));

// async global->LDS DMA, 16B per lane; lds dest = wave-uniform base + lane*16
__device__ __forceinline__ void gl2lds16(const void* g, void* l) {
    __builtin_amdgcn_global_load_lds(
        (const __attribute__((address_space(1))) unsigned int*)g,
        (__attribute__((address_space(3))) unsigned int*)l, 16, 0, 0);
}

// ---- fused LN (blocks 0..8191) + 3-weight convert (blocks 8192..11263) ----
__global__ __launch_bounds__(256) void lnconv_k(const float* __restrict__ x,
                                                const float* __restrict__ g,
                                                const float* __restrict__ be,
                                                bf16* __restrict__ xn,
                                                const float* __restrict__ Wq,
                                                const float* __restrict__ Wk,
                                                const float* __restrict__ Wv,
                                                bf16* __restrict__ Wqk,
                                                bf16* __restrict__ Wvd) {
    int t = threadIdx.x;
    if (blockIdx.x < MROWS) {
        int row = blockIdx.x;
        float4 v4 = ((const float4*)(x + (size_t)row * HH))[t];
        const float* v = (const float*)&v4;
        float s = v[0] + v[1] + v[2] + v[3];
        float s2 = v[0]*v[0] + v[1]*v[1] + v[2]*v[2] + v[3]*v[3];
#pragma unroll
        for (int off = 32; off > 0; off >>= 1) {
            s  += __shfl_down(s,  off);
            s2 += __shfl_down(s2, off);
        }
        __shared__ float red[8];
        if ((t & 63) == 0) { red[t >> 6] = s; red[(t >> 6) + 4] = s2; }
        __syncthreads();
        s  = red[0] + red[1] + red[2] + red[3];
        s2 = red[4] + red[5] + red[6] + red[7];
        float mu  = s * (1.f / HH);
        float var = s2 * (1.f / HH) - mu * mu;
        float rs  = rsqrtf(var + 1e-5f);
        float4 g4 = ((const float4*)g)[t];
        float4 b4 = ((const float4*)be)[t];
        const float* gv = (const float*)&g4;
        const float* bv = (const float*)&b4;
        bf16x4 o;
#pragma unroll
        for (int z = 0; z < 4; z++) o[z] = (bf16)((v[z] - mu) * rs * gv[z] + bv[z]);
        ((bf16x4*)(xn + (size_t)row * HH))[t] = o;
    } else {
        int blk = blockIdx.x - MROWS;          // 0..3071
        int sel = blk >> 10;
        int idx = (blk & 1023) * 256 + t;
        const float* src = (sel == 0) ? Wq : (sel == 1) ? Wk : Wv;
        bf16* dst = (sel == 0) ? Wqk : (sel == 1) ? (Wqk + (size_t)HH * HH) : Wvd;
        float4 v4 = ((const float4*)src)[idx];
        const float* v = (const float*)&v4;
        bf16x4 o;
#pragma unroll
        for (int z = 0; z < 4; z++) o[z] = (bf16)v[z];
        ((bf16x4*)dst)[idx] = o;
    }
}

// ---------------- Weight convert f32 -> bf16 (Wo, post-V-GEMM) ----------------
__global__ __launch_bounds__(256) void convw_k(const float* __restrict__ W,
                                               bf16* __restrict__ Wb) {
    int idx = blockIdx.x * 256 + threadIdx.x;
    float4 v4 = ((const float4*)W)[idx];
    const float* v = (const float*)&v4;
    bf16x4 o;
#pragma unroll
    for (int z = 0; z < 4; z++) o[z] = (bf16)v[z];
    ((bf16x4*)Wb)[idx] = o;
}

// ===================================================================================
// r12 GEMM: verified m97 BK=32 body (r2-r7 bits) + 3-LDS-buffer single-barrier
// 2-deep-prefetch schedule:
//   iter kt: [vmcnt(4); s_barrier] -> stage tile kt+2 into buf (kt+2)%3 -> compute
//   buf kt%3. One barrier + one counted vmcnt per iter (r9 had 2 barriers, 1-deep).
//   Ledger (4 loads/wave/tile): at gate outstanding = kt+1(4) [+kt] -> vmcnt(4)
//   proves kt resident; cross-wave via vmcnt-before-barrier. Race-free: stage
//   target buf ≡ (kt-1)%3 was last read in iter kt-1, and every wave passed this
//   iter's barrier only after finishing kt-1's MFMAs; next read (iter kt+2) is
//   gated by that iter's vmcnt(4).
//   LDS 3 x 16KB = 48KB -> 3 blocks/CU (12 waves); prefetch cover = 2 iterations.
// ===================================================================================

// ---- fused QK: W = Wq||Wk (2048x1024), grid (64,16); n0<1024 -> Q else K ----
__global__ __launch_bounds__(256) void gemm_qk32_k(const bf16* __restrict__ A,
                                                   const bf16* __restrict__ W,
                                                   bf16* __restrict__ Qo,
                                                   bf16* __restrict__ Ko) {
    const int K = HH, N = HH;
    __shared__ __align__(16) bf16 As[3][128 * 32];
    __shared__ __align__(16) bf16 Ws[3][128 * 32];
    int m0 = blockIdx.x * 128, n0 = blockIdx.y * 128;
    int t = threadIdx.x, lane = t & 63, w = t >> 6;
    int wm = w >> 1, wn = w & 1;
    int quad = lane >> 4, cl = lane & 15;
    int rA0 = w * 16 + (lane >> 2);                    // + i*64
    int xa = (((lane & 3) ^ ((lane >> 3) & 3)) * 8);   // swizzled source col
    int pc = (quad ^ ((cl >> 1) & 3)) * 8;             // frag phys chunk offset
    floatx4 acc[4][4] = {};

    auto stage = [&](int kt, int sb) {
#pragma unroll
        for (int i = 0; i < 2; i++) {
            gl2lds16(&A[(size_t)(m0 + rA0 + i * 64) * K + kt * 32 + xa],
                     (char*)&As[sb][0] + w * 1024 + i * 4096);
            gl2lds16(&W[(size_t)(n0 + rA0 + i * 64) * K + kt * 32 + xa],
                     (char*)&Ws[sb][0] + w * 1024 + i * 4096);
        }
    };

    stage(0, 0); stage(1, 1);
#pragma unroll 1
    for (int kt = 0; kt < 32; ++kt) {
        if (kt < 31) asm volatile("s_waitcnt vmcnt(4)" ::: "memory");
        else         asm volatile("s_waitcnt vmcnt(0)" ::: "memory");
        __builtin_amdgcn_s_barrier();
        __builtin_amdgcn_sched_barrier(0);
        if (kt + 2 < 32) stage(kt + 2, (kt + 2) % 3);
        int p = kt % 3;
        bf16x8 af[4], bfr[4];
#pragma unroll
        for (int i = 0; i < 4; i++) af[i]  = *(const bf16x8*)&As[p][(wm * 64 + i * 16 + cl) * 32 + pc];
#pragma unroll
        for (int j = 0; j < 4; j++) bfr[j] = *(const bf16x8*)&Ws[p][(wn * 64 + j * 16 + cl) * 32 + pc];
#pragma unroll
        for (int i = 0; i < 4; i++)
#pragma unroll
            for (int j = 0; j < 4; j++)
                acc[i][j] = __builtin_amdgcn_mfma_f32_16x16x32_bf16(af[i], bfr[j], acc[i][j], 0, 0, 0);
    }
    bool isQ = (n0 < 1024);
    bf16* Cd = isQ ? Qo : Ko;
    int nb = isQ ? n0 : (n0 - 1024);
#pragma unroll
    for (int i = 0; i < 4; i++)
#pragma unroll
        for (int j = 0; j < 4; j++) {
            int gr = m0 + wm * 64 + i * 16 + quad * 4;
            int gc = nb + wn * 64 + j * 16 + cl;
#pragma unroll
            for (int rg = 0; rg < 4; rg++)
                Cd[(size_t)(gr + rg) * N + gc] = (bf16)acc[i][j][rg];
        }
}

// ---- V projection, V^T epilogue [b][h][d][T]; grid (64,8) ----
__global__ __launch_bounds__(256) void gemm_v32_k(const bf16* __restrict__ A,
                                                  const bf16* __restrict__ W,
                                                  bf16* __restrict__ C) {
    const int K = HH;
    __shared__ __align__(16) bf16 As[3][128 * 32];
    __shared__ __align__(16) bf16 Ws[3][128 * 32];
    int m0 = blockIdx.x * 128, n0 = blockIdx.y * 128;
    int t = threadIdx.x, lane = t & 63, w = t >> 6;
    int wm = w >> 1, wn = w & 1;
    int quad = lane >> 4, cl = lane & 15;
    int rA0 = w * 16 + (lane >> 2);
    int xa = (((lane & 3) ^ ((lane >> 3) & 3)) * 8);
    int pc = (quad ^ ((cl >> 1) & 3)) * 8;
    floatx4 acc[4][4] = {};

    auto stage = [&](int kt, int sb) {
#pragma unroll
        for (int i = 0; i < 2; i++) {
            gl2lds16(&A[(size_t)(m0 + rA0 + i * 64) * K + kt * 32 + xa],
                     (char*)&As[sb][0] + w * 1024 + i * 4096);
            gl2lds16(&W[(size_t)(n0 + rA0 + i * 64) * K + kt * 32 + xa],
                     (char*)&Ws[sb][0] + w * 1024 + i * 4096);
        }
    };

    stage(0, 0); stage(1, 1);
#pragma unroll 1
    for (int kt = 0; kt < 32; ++kt) {
        if (kt < 31) asm volatile("s_waitcnt vmcnt(4)" ::: "memory");
        else         asm volatile("s_waitcnt vmcnt(0)" ::: "memory");
        __builtin_amdgcn_s_barrier();
        __builtin_amdgcn_sched_barrier(0);
        if (kt + 2 < 32) stage(kt + 2, (kt + 2) % 3);
        int p = kt % 3;
        bf16x8 af[4], bfr[4];
#pragma unroll
        for (int i = 0; i < 4; i++) af[i]  = *(const bf16x8*)&As[p][(wm * 64 + i * 16 + cl) * 32 + pc];
#pragma unroll
        for (int j = 0; j < 4; j++) bfr[j] = *(const bf16x8*)&Ws[p][(wn * 64 + j * 16 + cl) * 32 + pc];
#pragma unroll
        for (int i = 0; i < 4; i++)
#pragma unroll
            for (int j = 0; j < 4; j++)
                acc[i][j] = __builtin_amdgcn_mfma_f32_16x16x32_bf16(af[i], bfr[j], acc[i][j], 0, 0, 0);
    }
#pragma unroll
    for (int i = 0; i < 4; i++)
#pragma unroll
        for (int j = 0; j < 4; j++) {
            int gr = m0 + wm * 64 + i * 16 + quad * 4;
            int gc = n0 + wn * 64 + j * 16 + cl;
            int bb2 = gr >> 11, tt2 = gr & 2047;
            int hh2 = gc >> 7,  dd2 = gc & 127;
            bf16x4 o4;
#pragma unroll
            for (int rg = 0; rg < 4; rg++) o4[rg] = (bf16)acc[i][j][rg];
            *(bf16x4*)&C[((size_t)(bb2 * NHEADS + hh2) * HDIM + dd2) * TT + tt2] = o4;
        }
}

// ---- final GEMM: out_f32 = A*Wo^T + R; grid (64,8) ----
__global__ __launch_bounds__(256) void gemm_fin32_k(const bf16* __restrict__ A,
                                                    const bf16* __restrict__ W,
                                                    const float* __restrict__ R,
                                                    float* __restrict__ C) {
    const int K = HH, N = HH;
    __shared__ __align__(16) bf16 As[3][128 * 32];
    __shared__ __align__(16) bf16 Ws[3][128 * 32];
    int m0 = blockIdx.x * 128, n0 = blockIdx.y * 128;
    int t = threadIdx.x, lane = t & 63, w = t >> 6;
    int wm = w >> 1, wn = w & 1;
    int quad = lane >> 4, cl = lane & 15;
    int rA0 = w * 16 + (lane >> 2);
    int xa = (((lane & 3) ^ ((lane >> 3) & 3)) * 8);
    int pc = (quad ^ ((cl >> 1) & 3)) * 8;
    floatx4 acc[4][4] = {};

    auto stage = [&](int kt, int sb) {
#pragma unroll
        for (int i = 0; i < 2; i++) {
            gl2lds16(&A[(size_t)(m0 + rA0 + i * 64) * K + kt * 32 + xa],
                     (char*)&As[sb][0] + w * 1024 + i * 4096);
            gl2lds16(&W[(size_t)(n0 + rA0 + i * 64) * K + kt * 32 + xa],
                     (char*)&Ws[sb][0] + w * 1024 + i * 4096);
        }
    };

    stage(0, 0); stage(1, 1);
#pragma unroll 1
    for (int kt = 0; kt < 32; ++kt) {
        if (kt < 31) asm volatile("s_waitcnt vmcnt(4)" ::: "memory");
        else         asm volatile("s_waitcnt vmcnt(0)" ::: "memory");
        __builtin_amdgcn_s_barrier();
        __builtin_amdgcn_sched_barrier(0);
        if (kt + 2 < 32) stage(kt + 2, (kt + 2) % 3);
        int p = kt % 3;
        bf16x8 af[4], bfr[4];
#pragma unroll
        for (int i = 0; i < 4; i++) af[i]  = *(const bf16x8*)&As[p][(wm * 64 + i * 16 + cl) * 32 + pc];
#pragma unroll
        for (int j = 0; j < 4; j++) bfr[j] = *(const bf16x8*)&Ws[p][(wn * 64 + j * 16 + cl) * 32 + pc];
#pragma unroll
        for (int i = 0; i < 4; i++)
#pragma unroll
            for (int j = 0; j < 4; j++)
                acc[i][j] = __builtin_amdgcn_mfma_f32_16x16x32_bf16(af[i], bfr[j], acc[i][j], 0, 0, 0);
    }
#pragma unroll
    for (int i = 0; i < 4; i++)
#pragma unroll
        for (int j = 0; j < 4; j++)
#pragma unroll
            for (int rg = 0; rg < 4; rg++) {
                int gr = m0 + wm * 64 + i * 16 + quad * 4 + rg;
                int gc = n0 + wn * 64 + j * 16 + cl;
                C[(size_t)gr * N + gc] = acc[i][j][rg] + R[(size_t)gr * N + gc];
            }
}

// ---- Flash attention (causal), 64-row Q tiles (r11 exact, verified 84 µs) ----
// K single + V double buffered (48KB, 3 blocks/CU); V(kt+1) top-staged, K(kt+1)
// post-S; single S-gate vmcnt(4); XCD-locality swizzle; __expf; T13 defer-max;
// T5 setprio around MFMA clusters.
__global__ __launch_bounds__(256) void attn_k(const bf16* __restrict__ Q,
                                              const bf16* __restrict__ Kg,
                                              const bf16* __restrict__ Vt,
                                              bf16* __restrict__ O) {
    __shared__ __align__(16) bf16 Ks[64 * 128];       // 16384 B (single)
    __shared__ __align__(16) bf16 Vs2[2][128 * 64];   // 2x16384 B -> 49152 B total

    int wid = blockIdx.x;            // 1024 blocks
    int xcd = wid & 7;
    int idx = wid >> 3;              // 0..127
    int qt  = 31 - (idx >> 2);       // long blocks first, all groups
    int grp = (idx & 3) * 8 + xcd;   // 0..31 ; all qt of grp share an XCD
    int b = grp >> 3, h = grp & 7;

    int t = threadIdx.x, lane = t & 63, w = t >> 6;
    int quad = lane >> 4, cl = lane & 15;
    size_t rowbase = (size_t)b * TT;
    int q0 = qt * 64;
    size_t hcol = (size_t)h * HDIM;
    size_t vtbase = (size_t)(b * NHEADS + h) * HDIM * TT;

    bf16x8 qf[4];
#pragma unroll
    for (int kk = 0; kk < 4; kk++)
        qf[kk] = *(const bf16x8*)&Q[(rowbase + q0 + w * 16 + cl) * HH + hcol + kk * 32 + quad * 8];

    auto stageK = [&](int ktf) {
        const bf16* kbase = &Kg[(rowbase + (size_t)ktf * 64) * HH + hcol];
#pragma unroll
        for (int i = 0; i < 4; i++) {
            int rk = w * 16 + i * 4 + (lane >> 4);
            int xk = ((lane & 15) ^ ((rk >> 1) & 7)) * 8;
            gl2lds16(kbase + (size_t)rk * HH + xk, (char*)&Ks[0] + (w * 4 + i) * 1024);
        }
    };
    auto stageV = [&](int ktf, int bb) {
        const bf16* vbase = &Vt[vtbase + (size_t)ktf * 64];
#pragma unroll
        for (int i = 0; i < 4; i++) {
            int rv = w * 32 + i * 8 + (lane >> 3);
            int xv = ((lane & 7) ^ (rv & 7)) * 8;
            gl2lds16(vbase + (size_t)rv * TT + xv, (char*)&Vs2[bb][0] + (w * 4 + i) * 1024);
        }
    };

    float m_i = -1e30f, l_i = 0.f;
    floatx4 acc[8] = {};
    const float scale = 0.08838834764831845f;  // 1/sqrt(128)
    int kswz = ((cl >> 1) & 7);
    int vswz = (cl & 7);
    int qglob = q0 + w * 16 + cl;

    stageV(0, 0);
    stageK(0);

    int p = 0;
    for (int kt = 0; kt <= qt; kt++) {
        bool lastit = (kt == qt);
        if (!lastit) stageV(kt + 1, p ^ 1);

        if (!lastit) asm volatile("s_waitcnt vmcnt(4)" ::: "memory");
        else         asm volatile("s_waitcnt vmcnt(0)" ::: "memory");
        __builtin_amdgcn_s_barrier();
        __builtin_amdgcn_sched_barrier(0);

        floatx4 sacc[4] = {};
        __builtin_amdgcn_s_setprio(1);
#pragma unroll
        for (int kk = 0; kk < 4; kk++)
#pragma unroll
            for (int jj = 0; jj < 4; jj++) {
                bf16x8 ak = *(const bf16x8*)&Ks[(jj * 16 + cl) * 128 + ((kk * 4 + quad) ^ kswz) * 8];
                sacc[jj] = __builtin_amdgcn_mfma_f32_16x16x32_bf16(ak, qf[kk], sacc[jj], 0, 0, 0);
            }
        __builtin_amdgcn_s_setprio(0);

        if (!lastit) {
            __builtin_amdgcn_s_barrier();
            __builtin_amdgcn_sched_barrier(0);
            stageK(kt + 1);
        }

        float pp[4][4];
        {
            float mx = -1e30f;
#pragma unroll
            for (int jj = 0; jj < 4; jj++)
#pragma unroll
                for (int rg = 0; rg < 4; rg++) {
                    float sv = sacc[jj][rg] * scale;
                    if (lastit && (kt * 64 + jj * 16 + quad * 4 + rg) > qglob) sv = -1e30f;
                    pp[jj][rg] = sv;
                    mx = fmaxf(mx, sv);
                }
            mx = fmaxf(mx, __shfl_xor(mx, 16));
            mx = fmaxf(mx, __shfl_xor(mx, 32));
            // T13 defer-max: only rescale when some row's max grew by > 8
            if (__any(mx > m_i + 8.0f)) {
                float mn = fmaxf(m_i, mx);
                float alpha = __expf(m_i - mn);
                m_i = mn;
                l_i *= alpha;
#pragma unroll
                for (int nt = 0; nt < 8; nt++) acc[nt] *= alpha;
            }
            float sum = 0.f;
#pragma unroll
            for (int jj = 0; jj < 4; jj++)
#pragma unroll
                for (int rg = 0; rg < 4; rg++) {
                    float pe = __expf(pp[jj][rg] - m_i);
                    pp[jj][rg] = pe;
                    sum += pe;
                }
            sum += __shfl_xor(sum, 16);
            sum += __shfl_xor(sum, 32);
            l_i += sum;
        }

        int pk[4][2];
#pragma unroll
        for (int jj = 0; jj < 4; jj++) {
            union { bf16x4 v; int i2[2]; } u;
#pragma unroll
            for (int rg = 0; rg < 4; rg++) u.v[rg] = (bf16)pp[jj][rg];
            pk[jj][0] = u.i2[0];
            pk[jj][1] = u.i2[1];
        }

        int La = ((2 * quad) & 3) * 16 + cl;
        int Lb = ((2 * quad + 1) & 3) * 16 + cl;
        bool hi = (quad >> 1) & 1;
#pragma unroll
        for (int kti = 0; kti < 2; kti++) {
            int j0 = kti * 2, j1 = kti * 2 + 1;
            union { bf16x8 v; int i4[4]; } pu;
            {
                int a0x = __shfl(pk[j0][0], La), a0y = __shfl(pk[j0][1], La);
                int a1x = __shfl(pk[j1][0], La), a1y = __shfl(pk[j1][1], La);
                int b0x = __shfl(pk[j0][0], Lb), b0y = __shfl(pk[j0][1], Lb);
                int b1x = __shfl(pk[j1][0], Lb), b1y = __shfl(pk[j1][1], Lb);
                pu.i4[0] = hi ? a1x : a0x;
                pu.i4[1] = hi ? a1y : a0y;
                pu.i4[2] = hi ? b1x : b0x;
                pu.i4[3] = hi ? b1y : b0y;
            }
            __builtin_amdgcn_s_setprio(1);
#pragma unroll
            for (int nt = 0; nt < 8; nt++) {
                bf16x8 av = *(const bf16x8*)&Vs2[p][(nt * 16 + cl) * 64 + ((kti * 4 + quad) ^ vswz) * 8];
                acc[nt] = __builtin_amdgcn_mfma_f32_16x16x32_bf16(av, pu.v, acc[nt], 0, 0, 0);
            }
            __builtin_amdgcn_s_setprio(0);
        }

        if (!lastit) {
            __builtin_amdgcn_s_barrier();
            __builtin_amdgcn_sched_barrier(0);
        }
        p ^= 1;
    }

    float linv = 1.f / l_i;
#pragma unroll
    for (int nt = 0; nt < 8; nt++) {
        bf16x4 o4;
#pragma unroll
        for (int rg = 0; rg < 4; rg++) o4[rg] = (bf16)(acc[nt][rg] * linv);
        *(bf16x4*)&O[(rowbase + q0 + w * 16 + cl) * HH + hcol + nt * 16 + quad * 4] = o4;
    }
}

extern "C" void kernel_launch(void* const* d_in, const int* in_sizes, int n_in,
                              void* d_out, int out_size, void* d_ws, size_t ws_size,
                              hipStream_t stream) {
    const float* x     = (const float*)d_in[0];
    const float* gamma = (const float*)d_in[1];
    const float* beta  = (const float*)d_in[2];
    const float* Wq    = (const float*)d_in[3];
    const float* Wk    = (const float*)d_in[4];
    const float* Wv    = (const float*)d_in[5];
    const float* Wo    = (const float*)d_in[6];
    float* out = (float*)d_out;

    const size_t NELEM = (size_t)MROWS * HH;
    // ws (35.7 MB): Qb bf16 (16.8) + Vb bf16 (16.8) + Wslot bf16 (2.1).
    // Wqk (4.2 MB, Wq||Wk) lives at the Vb region — dead before V-GEMM writes Vb.
    // Wslot: Wv until V-GEMM, then Wo (converted post-V-GEMM, pre-attn).
    // d_out: Kb bf16 + xnb bf16 — both dead before final GEMM overwrites d_out.
    bf16* Qb    = (bf16*)d_ws;
    bf16* Vb    = Qb + NELEM;          // V^T layout [b][h][d][T]
    bf16* Wslot = Vb + NELEM;
    bf16* Wqk   = Vb;                  // 2048x1024 bf16, transient
    bf16* Kb    = (bf16*)d_out;
    bf16* xnb   = (bf16*)d_out + NELEM;

    lnconv_k<<<MROWS + 3 * HH * HH / 1024, 256, 0, stream>>>(
        x, gamma, beta, xnb, Wq, Wk, Wv, Wqk, Wslot);
    gemm_qk32_k<<<dim3(MROWS / 128, 2 * HH / 128), 256, 0, stream>>>(xnb, Wqk, Qb, Kb);
    gemm_v32_k<<<dim3(MROWS / 128, HH / 128), 256, 0, stream>>>(xnb, Wslot, Vb);
    convw_k<<<HH * HH / 1024, 256, 0, stream>>>(Wo, Wslot);   // Wv dead; pre-attn
    attn_k<<<TT / 64 * NHEADS * BB, 256, 0, stream>>>(Qb, Kb, Vb, Qb);
    gemm_fin32_k<<<dim3(MROWS / 128, HH / 128), 256, 0, stream>>>(Qb, Wslot, x, out);
}

// Round 13
// 260.353 us; speedup vs baseline: 1.0778x; 1.0778x over previous
//
#include <hip/hip_runtime.h>
#include <hip/hip_bf16.h>

#define HH 1024
#define NHEADS 8
#define HDIM 128
#define BB 4
#define TT 2048
#define MROWS (BB*TT)   // 8192

typedef __bf16 bf16;
typedef __bf16 bf16x4 __attribute__((ext_vector_type(4)));
typedef __bf16 bf16x8 __attribute__((ext_vector_type(8)));
typedef float floatx4 __attribute__((ext_vector_type(4)));

// async global->LDS DMA, 16B per lane; lds dest = wave-uniform base + lane*16
__device__ __forceinline__ void gl2lds16(const void* g, void* l) {
    __builtin_amdgcn_global_load_lds(
        (const __attribute__((address_space(1))) unsigned int*)g,
        (__attribute__((address_space(3))) unsigned int*)l, 16, 0, 0);
}

// raw hardware 2^x (one VOP1; __expf = v_mul+v_exp, exp2f = libm wrapper)
__device__ __forceinline__ float exp2hw(float x) {
    float r;
    asm("v_exp_f32 %0, %1" : "=v"(r) : "v"(x));
    return r;
}

// ---- fused LN (blocks 0..8191) + 3-weight convert (blocks 8192..11263) ----
__global__ __launch_bounds__(256) void lnconv_k(const float* __restrict__ x,
                                                const float* __restrict__ g,
                                                const float* __restrict__ be,
                                                bf16* __restrict__ xn,
                                                const float* __restrict__ Wq,
                                                const float* __restrict__ Wk,
                                                const float* __restrict__ Wv,
                                                bf16* __restrict__ Wqk,
                                                bf16* __restrict__ Wvd) {
    int t = threadIdx.x;
    if (blockIdx.x < MROWS) {
        int row = blockIdx.x;
        float4 v4 = ((const float4*)(x + (size_t)row * HH))[t];
        const float* v = (const float*)&v4;
        float s = v[0] + v[1] + v[2] + v[3];
        float s2 = v[0]*v[0] + v[1]*v[1] + v[2]*v[2] + v[3]*v[3];
#pragma unroll
        for (int off = 32; off > 0; off >>= 1) {
            s  += __shfl_down(s,  off);
            s2 += __shfl_down(s2, off);
        }
        __shared__ float red[8];
        if ((t & 63) == 0) { red[t >> 6] = s; red[(t >> 6) + 4] = s2; }
        __syncthreads();
        s  = red[0] + red[1] + red[2] + red[3];
        s2 = red[4] + red[5] + red[6] + red[7];
        float mu  = s * (1.f / HH);
        float var = s2 * (1.f / HH) - mu * mu;
        float rs  = rsqrtf(var + 1e-5f);
        float4 g4 = ((const float4*)g)[t];
        float4 b4 = ((const float4*)be)[t];
        const float* gv = (const float*)&g4;
        const float* bv = (const float*)&b4;
        bf16x4 o;
#pragma unroll
        for (int z = 0; z < 4; z++) o[z] = (bf16)((v[z] - mu) * rs * gv[z] + bv[z]);
        ((bf16x4*)(xn + (size_t)row * HH))[t] = o;
    } else {
        int blk = blockIdx.x - MROWS;          // 0..3071
        int sel = blk >> 10;
        int idx = (blk & 1023) * 256 + t;
        const float* src = (sel == 0) ? Wq : (sel == 1) ? Wk : Wv;
        bf16* dst = (sel == 0) ? Wqk : (sel == 1) ? (Wqk + (size_t)HH * HH) : Wvd;
        float4 v4 = ((const float4*)src)[idx];
        const float* v = (const float*)&v4;
        bf16x4 o;
#pragma unroll
        for (int z = 0; z < 4; z++) o[z] = (bf16)v[z];
        ((bf16x4*)dst)[idx] = o;
    }
}

// ---------------- Weight convert f32 -> bf16 (Wo, post-V-GEMM) ----------------
__global__ __launch_bounds__(256) void convw_k(const float* __restrict__ W,
                                               bf16* __restrict__ Wb) {
    int idx = blockIdx.x * 256 + threadIdx.x;
    float4 v4 = ((const float4*)W)[idx];
    const float* v = (const float*)&v4;
    bf16x4 o;
#pragma unroll
    for (int z = 0; z < 4; z++) o[z] = (bf16)v[z];
    ((bf16x4*)Wb)[idx] = o;
}

// ===================================================================================
// LOCKED GEMM (r9/r11 best-measured, ~505 TF): 128x128 tile, BK=64, 2-phase
// counted-vmcnt prefetch. Double-buffered LDS (2x32KB=64KB, 2 blocks/CU); issue tile
// kt+1's DMA at TOP of iter kt; gate vmcnt(8); end-of-iter barrier protects the
// staged buffer. [r10: 256^2@1blk/CU regressed; r12: BK=32 3-buf regressed —
// structure churn around this point is negative-EV.]
// ===================================================================================

// ---- fused QK: W = Wq||Wk (2048x1024), grid (64,16); n0<1024 -> Q else K ----
__global__ __launch_bounds__(256) void gemm_qk64_k(const bf16* __restrict__ A,
                                                   const bf16* __restrict__ W,
                                                   bf16* __restrict__ Qo,
                                                   bf16* __restrict__ Ko) {
    const int K = HH, N = HH;
    __shared__ __align__(16) bf16 As[2][128 * 64];
    __shared__ __align__(16) bf16 Ws[2][128 * 64];
    int m0 = blockIdx.x * 128, n0 = blockIdx.y * 128;
    int t = threadIdx.x, lane = t & 63, w = t >> 6;
    int wm = w >> 1, wn = w & 1;
    int quad = lane >> 4, cl = lane & 15;
    int r8v = lane >> 3;                   // 0..7
    int xa = ((lane & 7) ^ r8v) * 8;       // swizzled source col (elems)
    int rowb = w * 8 + r8v;                // + i*32
    int psw = cl & 7;
    floatx4 acc[4][4] = {};

    auto stage = [&](int kt, int sb) {
#pragma unroll
        for (int i = 0; i < 4; i++) {
            gl2lds16(&A[(size_t)(m0 + i * 32 + rowb) * K + kt * 64 + xa],
                     (char*)&As[sb][0] + i * 4096 + w * 1024);
            gl2lds16(&W[(size_t)(n0 + i * 32 + rowb) * K + kt * 64 + xa],
                     (char*)&Ws[sb][0] + i * 4096 + w * 1024);
        }
    };

    stage(0, 0);
#pragma unroll 1
    for (int kt = 0; kt < 16; ++kt) {
        int p = kt & 1;
        bool st = (kt + 1) < 16;
        if (st) stage(kt + 1, p ^ 1);
        if (st) asm volatile("s_waitcnt vmcnt(8)" ::: "memory");
        else    asm volatile("s_waitcnt vmcnt(0)" ::: "memory");
        __builtin_amdgcn_s_barrier();
        __builtin_amdgcn_sched_barrier(0);
#pragma unroll
        for (int ks = 0; ks < 2; ks++) {
            bf16x8 af[4], bfr[4];
#pragma unroll
            for (int i = 0; i < 4; i++) af[i]  = *(const bf16x8*)&As[p][(wm * 64 + i * 16 + cl) * 64 + (((ks * 4 + quad) ^ psw) * 8)];
#pragma unroll
            for (int j = 0; j < 4; j++) bfr[j] = *(const bf16x8*)&Ws[p][(wn * 64 + j * 16 + cl) * 64 + (((ks * 4 + quad) ^ psw) * 8)];
#pragma unroll
            for (int i = 0; i < 4; i++)
#pragma unroll
                for (int j = 0; j < 4; j++)
                    acc[i][j] = __builtin_amdgcn_mfma_f32_16x16x32_bf16(af[i], bfr[j], acc[i][j], 0, 0, 0);
        }
        __builtin_amdgcn_s_barrier();      // all reads of buf p done before next stage
        __builtin_amdgcn_sched_barrier(0);
    }
    bool isQ = (n0 < 1024);
    bf16* Cd = isQ ? Qo : Ko;
    int nb = isQ ? n0 : (n0 - 1024);
#pragma unroll
    for (int i = 0; i < 4; i++)
#pragma unroll
        for (int j = 0; j < 4; j++) {
            int gr = m0 + wm * 64 + i * 16 + quad * 4;
            int gc = nb + wn * 64 + j * 16 + cl;
#pragma unroll
            for (int rg = 0; rg < 4; rg++)
                Cd[(size_t)(gr + rg) * N + gc] = (bf16)acc[i][j][rg];
        }
}

// ---- V projection, V^T epilogue [b][h][d][T]; grid (64,8) ----
__global__ __launch_bounds__(256) void gemm_v64_k(const bf16* __restrict__ A,
                                                  const bf16* __restrict__ W,
                                                  bf16* __restrict__ C) {
    const int K = HH;
    __shared__ __align__(16) bf16 As[2][128 * 64];
    __shared__ __align__(16) bf16 Ws[2][128 * 64];
    int m0 = blockIdx.x * 128, n0 = blockIdx.y * 128;
    int t = threadIdx.x, lane = t & 63, w = t >> 6;
    int wm = w >> 1, wn = w & 1;
    int quad = lane >> 4, cl = lane & 15;
    int r8v = lane >> 3;
    int xa = ((lane & 7) ^ r8v) * 8;
    int rowb = w * 8 + r8v;
    int psw = cl & 7;
    floatx4 acc[4][4] = {};

    auto stage = [&](int kt, int sb) {
#pragma unroll
        for (int i = 0; i < 4; i++) {
            gl2lds16(&A[(size_t)(m0 + i * 32 + rowb) * K + kt * 64 + xa],
                     (char*)&As[sb][0] + i * 4096 + w * 1024);
            gl2lds16(&W[(size_t)(n0 + i * 32 + rowb) * K + kt * 64 + xa],
                     (char*)&Ws[sb][0] + i * 4096 + w * 1024);
        }
    };

    stage(0, 0);
#pragma unroll 1
    for (int kt = 0; kt < 16; ++kt) {
        int p = kt & 1;
        bool st = (kt + 1) < 16;
        if (st) stage(kt + 1, p ^ 1);
        if (st) asm volatile("s_waitcnt vmcnt(8)" ::: "memory");
        else    asm volatile("s_waitcnt vmcnt(0)" ::: "memory");
        __builtin_amdgcn_s_barrier();
        __builtin_amdgcn_sched_barrier(0);
#pragma unroll
        for (int ks = 0; ks < 2; ks++) {
            bf16x8 af[4], bfr[4];
#pragma unroll
            for (int i = 0; i < 4; i++) af[i]  = *(const bf16x8*)&As[p][(wm * 64 + i * 16 + cl) * 64 + (((ks * 4 + quad) ^ psw) * 8)];
#pragma unroll
            for (int j = 0; j < 4; j++) bfr[j] = *(const bf16x8*)&Ws[p][(wn * 64 + j * 16 + cl) * 64 + (((ks * 4 + quad) ^ psw) * 8)];
#pragma unroll
            for (int i = 0; i < 4; i++)
#pragma unroll
                for (int j = 0; j < 4; j++)
                    acc[i][j] = __builtin_amdgcn_mfma_f32_16x16x32_bf16(af[i], bfr[j], acc[i][j], 0, 0, 0);
        }
        __builtin_amdgcn_s_barrier();
        __builtin_amdgcn_sched_barrier(0);
    }
#pragma unroll
    for (int i = 0; i < 4; i++)
#pragma unroll
        for (int j = 0; j < 4; j++) {
            int gr = m0 + wm * 64 + i * 16 + quad * 4;
            int gc = n0 + wn * 64 + j * 16 + cl;
            int bb2 = gr >> 11, tt2 = gr & 2047;
            int hh2 = gc >> 7,  dd2 = gc & 127;
            bf16x4 o4;
#pragma unroll
            for (int rg = 0; rg < 4; rg++) o4[rg] = (bf16)acc[i][j][rg];
            *(bf16x4*)&C[((size_t)(bb2 * NHEADS + hh2) * HDIM + dd2) * TT + tt2] = o4;
        }
}

// ---- final GEMM: out_f32 = A*Wo^T + R; grid (64,8) ----
__global__ __launch_bounds__(256) void gemm_fin64_k(const bf16* __restrict__ A,
                                                    const bf16* __restrict__ W,
                                                    const float* __restrict__ R,
                                                    float* __restrict__ C) {
    const int K = HH, N = HH;
    __shared__ __align__(16) bf16 As[2][128 * 64];
    __shared__ __align__(16) bf16 Ws[2][128 * 64];
    int m0 = blockIdx.x * 128, n0 = blockIdx.y * 128;
    int t = threadIdx.x, lane = t & 63, w = t >> 6;
    int wm = w >> 1, wn = w & 1;
    int quad = lane >> 4, cl = lane & 15;
    int r8v = lane >> 3;
    int xa = ((lane & 7) ^ r8v) * 8;
    int rowb = w * 8 + r8v;
    int psw = cl & 7;
    floatx4 acc[4][4] = {};

    auto stage = [&](int kt, int sb) {
#pragma unroll
        for (int i = 0; i < 4; i++) {
            gl2lds16(&A[(size_t)(m0 + i * 32 + rowb) * K + kt * 64 + xa],
                     (char*)&As[sb][0] + i * 4096 + w * 1024);
            gl2lds16(&W[(size_t)(n0 + i * 32 + rowb) * K + kt * 64 + xa],
                     (char*)&Ws[sb][0] + i * 4096 + w * 1024);
        }
    };

    stage(0, 0);
#pragma unroll 1
    for (int kt = 0; kt < 16; ++kt) {
        int p = kt & 1;
        bool st = (kt + 1) < 16;
        if (st) stage(kt + 1, p ^ 1);
        if (st) asm volatile("s_waitcnt vmcnt(8)" ::: "memory");
        else    asm volatile("s_waitcnt vmcnt(0)" ::: "memory");
        __builtin_amdgcn_s_barrier();
        __builtin_amdgcn_sched_barrier(0);
#pragma unroll
        for (int ks = 0; ks < 2; ks++) {
            bf16x8 af[4], bfr[4];
#pragma unroll
            for (int i = 0; i < 4; i++) af[i]  = *(const bf16x8*)&As[p][(wm * 64 + i * 16 + cl) * 64 + (((ks * 4 + quad) ^ psw) * 8)];
#pragma unroll
            for (int j = 0; j < 4; j++) bfr[j] = *(const bf16x8*)&Ws[p][(wn * 64 + j * 16 + cl) * 64 + (((ks * 4 + quad) ^ psw) * 8)];
#pragma unroll
            for (int i = 0; i < 4; i++)
#pragma unroll
                for (int j = 0; j < 4; j++)
                    acc[i][j] = __builtin_amdgcn_mfma_f32_16x16x32_bf16(af[i], bfr[j], acc[i][j], 0, 0, 0);
        }
        __builtin_amdgcn_s_barrier();
        __builtin_amdgcn_sched_barrier(0);
    }
#pragma unroll
    for (int i = 0; i < 4; i++)
#pragma unroll
        for (int j = 0; j < 4; j++)
#pragma unroll
            for (int rg = 0; rg < 4; rg++) {
                int gr = m0 + wm * 64 + i * 16 + quad * 4 + rg;
                int gc = n0 + wn * 64 + j * 16 + cl;
                C[(size_t)gr * N + gc] = acc[i][j][rg] + R[(size_t)gr * N + gc];
            }
}

// ---- Flash attention (causal), 64-row Q tiles (r11 structure, 84 µs) ----
// K single + V double buffered (48KB, 3 blocks/CU); V(kt+1) top-staged, K(kt+1)
// post-S; single S-gate vmcnt(4); XCD-locality swizzle; T13 defer-max; T5 setprio.
// r13 delta: log2-domain softmax — scale folded with log2(e), exp = raw v_exp_f32
// (1 VOP1 vs __expf's v_mul+v_exp; r7's exp2f regression was libm wrapper overhead).
__global__ __launch_bounds__(256) void attn_k(const bf16* __restrict__ Q,
                                              const bf16* __restrict__ Kg,
                                              const bf16* __restrict__ Vt,
                                              bf16* __restrict__ O) {
    __shared__ __align__(16) bf16 Ks[64 * 128];       // 16384 B (single)
    __shared__ __align__(16) bf16 Vs2[2][128 * 64];   // 2x16384 B -> 49152 B total

    int wid = blockIdx.x;            // 1024 blocks
    int xcd = wid & 7;
    int idx = wid >> 3;              // 0..127
    int qt  = 31 - (idx >> 2);       // long blocks first, all groups
    int grp = (idx & 3) * 8 + xcd;   // 0..31 ; all qt of grp share an XCD
    int b = grp >> 3, h = grp & 7;

    int t = threadIdx.x, lane = t & 63, w = t >> 6;
    int quad = lane >> 4, cl = lane & 15;
    size_t rowbase = (size_t)b * TT;
    int q0 = qt * 64;
    size_t hcol = (size_t)h * HDIM;
    size_t vtbase = (size_t)(b * NHEADS + h) * HDIM * TT;

    bf16x8 qf[4];
#pragma unroll
    for (int kk = 0; kk < 4; kk++)
        qf[kk] = *(const bf16x8*)&Q[(rowbase + q0 + w * 16 + cl) * HH + hcol + kk * 32 + quad * 8];

    auto stageK = [&](int ktf) {
        const bf16* kbase = &Kg[(rowbase + (size_t)ktf * 64) * HH + hcol];
#pragma unroll
        for (int i = 0; i < 4; i++) {
            int rk = w * 16 + i * 4 + (lane >> 4);
            int xk = ((lane & 15) ^ ((rk >> 1) & 7)) * 8;
            gl2lds16(kbase + (size_t)rk * HH + xk, (char*)&Ks[0] + (w * 4 + i) * 1024);
        }
    };
    auto stageV = [&](int ktf, int bb) {
        const bf16* vbase = &Vt[vtbase + (size_t)ktf * 64];
#pragma unroll
        for (int i = 0; i < 4; i++) {
            int rv = w * 32 + i * 8 + (lane >> 3);
            int xv = ((lane & 7) ^ (rv & 7)) * 8;
            gl2lds16(vbase + (size_t)rv * TT + xv, (char*)&Vs2[bb][0] + (w * 4 + i) * 1024);
        }
    };

    float m_i = -1e30f, l_i = 0.f;
    floatx4 acc[8] = {};
    const float scl2 = 0.12751743342283433f;  // log2(e)/sqrt(128)
    int kswz = ((cl >> 1) & 7);
    int vswz = (cl & 7);
    int qglob = q0 + w * 16 + cl;

    stageV(0, 0);
    stageK(0);

    int p = 0;
    for (int kt = 0; kt <= qt; kt++) {
        bool lastit = (kt == qt);
        if (!lastit) stageV(kt + 1, p ^ 1);

        if (!lastit) asm volatile("s_waitcnt vmcnt(4)" ::: "memory");
        else         asm volatile("s_waitcnt vmcnt(0)" ::: "memory");
        __builtin_amdgcn_s_barrier();
        __builtin_amdgcn_sched_barrier(0);

        floatx4 sacc[4] = {};
        __builtin_amdgcn_s_setprio(1);
#pragma unroll
        for (int kk = 0; kk < 4; kk++)
#pragma unroll
            for (int jj = 0; jj < 4; jj++) {
                bf16x8 ak = *(const bf16x8*)&Ks[(jj * 16 + cl) * 128 + ((kk * 4 + quad) ^ kswz) * 8];
                sacc[jj] = __builtin_amdgcn_mfma_f32_16x16x32_bf16(ak, qf[kk], sacc[jj], 0, 0, 0);
            }
        __builtin_amdgcn_s_setprio(0);

        if (!lastit) {
            __builtin_amdgcn_s_barrier();
            __builtin_amdgcn_sched_barrier(0);
            stageK(kt + 1);
        }

        float pp[4][4];
        {
            float mx = -1e30f;
#pragma unroll
            for (int jj = 0; jj < 4; jj++)
#pragma unroll
                for (int rg = 0; rg < 4; rg++) {
                    float sv = sacc[jj][rg] * scl2;    // log2 domain
                    if (lastit && (kt * 64 + jj * 16 + quad * 4 + rg) > qglob) sv = -1e30f;
                    pp[jj][rg] = sv;
                    mx = fmaxf(mx, sv);
                }
            mx = fmaxf(mx, __shfl_xor(mx, 16));
            mx = fmaxf(mx, __shfl_xor(mx, 32));
            // T13 defer-max (log2 units; bound 2^8 < e^8 — safer than verified ln form)
            if (__any(mx > m_i + 8.0f)) {
                float mn = fmaxf(m_i, mx);
                float alpha = exp2hw(m_i - mn);
                m_i = mn;
                l_i *= alpha;
#pragma unroll
                for (int nt = 0; nt < 8; nt++) acc[nt] *= alpha;
            }
            float sum = 0.f;
#pragma unroll
            for (int jj = 0; jj < 4; jj++)
#pragma unroll
                for (int rg = 0; rg < 4; rg++) {
                    float pe = exp2hw(pp[jj][rg] - m_i);
                    pp[jj][rg] = pe;
                    sum += pe;
                }
            sum += __shfl_xor(sum, 16);
            sum += __shfl_xor(sum, 32);
            l_i += sum;
        }

        int pk[4][2];
#pragma unroll
        for (int jj = 0; jj < 4; jj++) {
            union { bf16x4 v; int i2[2]; } u;
#pragma unroll
            for (int rg = 0; rg < 4; rg++) u.v[rg] = (bf16)pp[jj][rg];
            pk[jj][0] = u.i2[0];
            pk[jj][1] = u.i2[1];
        }

        int La = ((2 * quad) & 3) * 16 + cl;
        int Lb = ((2 * quad + 1) & 3) * 16 + cl;
        bool hi = (quad >> 1) & 1;
#pragma unroll
        for (int kti = 0; kti < 2; kti++) {
            int j0 = kti * 2, j1 = kti * 2 + 1;
            union { bf16x8 v; int i4[4]; } pu;
            {
                int a0x = __shfl(pk[j0][0], La), a0y = __shfl(pk[j0][1], La);
                int a1x = __shfl(pk[j1][0], La), a1y = __shfl(pk[j1][1], La);
                int b0x = __shfl(pk[j0][0], Lb), b0y = __shfl(pk[j0][1], Lb);
                int b1x = __shfl(pk[j1][0], Lb), b1y = __shfl(pk[j1][1], Lb);
                pu.i4[0] = hi ? a1x : a0x;
                pu.i4[1] = hi ? a1y : a0y;
                pu.i4[2] = hi ? b1x : b0x;
                pu.i4[3] = hi ? b1y : b0y;
            }
            __builtin_amdgcn_s_setprio(1);
#pragma unroll
            for (int nt = 0; nt < 8; nt++) {
                bf16x8 av = *(const bf16x8*)&Vs2[p][(nt * 16 + cl) * 64 + ((kti * 4 + quad) ^ vswz) * 8];
                acc[nt] = __builtin_amdgcn_mfma_f32_16x16x32_bf16(av, pu.v, acc[nt], 0, 0, 0);
            }
            __builtin_amdgcn_s_setprio(0);
        }

        if (!lastit) {
            __builtin_amdgcn_s_barrier();
            __builtin_amdgcn_sched_barrier(0);
        }
        p ^= 1;
    }

    float linv = 1.f / l_i;
#pragma unroll
    for (int nt = 0; nt < 8; nt++) {
        bf16x4 o4;
#pragma unroll
        for (int rg = 0; rg < 4; rg++) o4[rg] = (bf16)(acc[nt][rg] * linv);
        *(bf16x4*)&O[(rowbase + q0 + w * 16 + cl) * HH + hcol + nt * 16 + quad * 4] = o4;
    }
}

extern "C" void kernel_launch(void* const* d_in, const int* in_sizes, int n_in,
                              void* d_out, int out_size, void* d_ws, size_t ws_size,
                              hipStream_t stream) {
    const float* x     = (const float*)d_in[0];
    const float* gamma = (const float*)d_in[1];
    const float* beta  = (const float*)d_in[2];
    const float* Wq    = (const float*)d_in[3];
    const float* Wk    = (const float*)d_in[4];
    const float* Wv    = (const float*)d_in[5];
    const float* Wo    = (const float*)d_in[6];
    float* out = (float*)d_out;

    const size_t NELEM = (size_t)MROWS * HH;
    // ws (35.7 MB): Qb bf16 (16.8) + Vb bf16 (16.8) + Wslot bf16 (2.1).
    // Wqk (4.2 MB, Wq||Wk) lives at the Vb region — dead before V-GEMM writes Vb.
    // Wslot: Wv until V-GEMM, then Wo (converted post-V-GEMM, pre-attn).
    // d_out: Kb bf16 + xnb bf16 — both dead before final GEMM overwrites d_out.
    bf16* Qb    = (bf16*)d_ws;
    bf16* Vb    = Qb + NELEM;          // V^T layout [b][h][d][T]
    bf16* Wslot = Vb + NELEM;
    bf16* Wqk   = Vb;                  // 2048x1024 bf16, transient
    bf16* Kb    = (bf16*)d_out;
    bf16* xnb   = (bf16*)d_out + NELEM;

    lnconv_k<<<MROWS + 3 * HH * HH / 1024, 256, 0, stream>>>(
        x, gamma, beta, xnb, Wq, Wk, Wv, Wqk, Wslot);
    gemm_qk64_k<<<dim3(MROWS / 128, 2 * HH / 128), 256, 0, stream>>>(xnb, Wqk, Qb, Kb);
    gemm_v64_k<<<dim3(MROWS / 128, HH / 128), 256, 0, stream>>>(xnb, Wslot, Vb);
    convw_k<<<HH * HH / 1024, 256, 0, stream>>>(Wo, Wslot);   // Wv dead; pre-attn
    attn_k<<<TT / 64 * NHEADS * BB, 256, 0, stream>>>(Qb, Kb, Vb, Qb);
    gemm_fin64_k<<<dim3(MROWS / 128, HH / 128), 256, 0, stream>>>(Qb, Wslot, x, out);
}